// Round 16
// baseline (524.336 us; speedup 1.0000x reference)
//
#include <hip/hip_runtime.h>
#include <math.h>

typedef unsigned short u16;
typedef unsigned int   u32;
typedef __attribute__((ext_vector_type(4))) float f32x4;   // native vec for nontemporal

// ---------------- scratch layout (fp32 offsets in d_ws; ws ~868 MB) ----------
#define OFF_AT    0          // |analytic|, [16][32768] (transposed)  524288 f
#define OFF_PT    524288     // angle,      [16][32768]               524288 f
#define OFF_WT    1048576    // W_sindy^T (deg1 folded), [1016][16]   16256 f
#define OFF_ZT    1064832    // z transposed [16][32768]              524288 f
#define OFF_TWC   1589120    // 1024 doubles (cos) = 2048 f
#define OFF_TWS   1591168    // 1024 doubles (sin)

// jac f4 ranges per kernel (exactly tile [0, 16777216)); all LO % 512 == 0
#define R1_LO 0
#define R1_HI 5592576
#define R2_LO 5592576
#define R2_HI 11185152
#define R3_LO 11185152
#define R3_HI 16777216

// jac[b,t,l,f] = W_enc[l,f]: flat f4 index i sources Wenc f4 (i & 511).
// Requires nth % 512 == 0 so the source index is loop-invariant.
__device__ __forceinline__ void jac_range(const float* __restrict__ Wenc,
                                          float* __restrict__ out_jac,
                                          int lo, int hi, int idx, int nth)
{
    const float* wsrc = Wenc + (size_t)((lo + idx) & 511) * 4;
    f32x4 w;
    w.x = wsrc[0]; w.y = wsrc[1]; w.z = wsrc[2]; w.w = wsrc[3];
    f32x4* j4 = (f32x4*)out_jac;
    for (int i = lo + idx; i < hi; i += nth)
        __builtin_nontemporal_store(w, j4 + i);
}

// ======================================================================
// K1: encoder + decoder; util blocks (2048..2115): passthroughs, folded
//     W_sindy^T, twiddles; writer blocks (>=2116): jac range R1.
// ======================================================================
__global__ __launch_bounds__(256) void k1_encdec(
    const float* __restrict__ x, const float* __restrict__ Wenc, const float* __restrict__ benc,
    const float* __restrict__ Wdec, const float* __restrict__ bdec,
    const float* __restrict__ Wsin,
    float* __restrict__ out_z, float* __restrict__ out_xhat,
    float* __restrict__ out_Ws, float* __restrict__ out_Wd,
    float* __restrict__ z_t, float* __restrict__ wt,
    double* __restrict__ twc_g, double* __restrict__ tws_g,
    float* __restrict__ out_jac)
{
    int tid = threadIdx.x;
    int blk = blockIdx.x;

    if (blk >= 2116) {       // 1024 writer blocks, nth = 262144 (512 | nth)
        jac_range(Wenc, out_jac, R1_LO, R1_HI, (blk - 2116) * 256 + tid, 262144);
        return;
    }
    if (blk >= 2048) {
        int t0 = (blk - 2048) * 256 + tid;   // 68 blocks -> 17408 threads
        if (t0 < 16256) {
            float v = Wsin[t0];
            out_Ws[t0] = v;                  // pass-through: ORIGINAL value
            int l = t0 / 1016;
            int d = t0 - l * 1016;
            // fold z-dup feature (968+d) into deg-1 row d
            if (d < 16) v += Wsin[t0 + 968];
            wt[d * 16 + l] = v;
        } else if (t0 < 17280) {             // 1024 twiddles, fp64, once
            int k = t0 - 16256;
            double ang = -6.283185307179586476925286766559 * (double)k / 2048.0;
            double s_, c_;
            sincos(ang, &s_, &c_);
            twc_g[k] = c_;
            tws_g[k] = s_;
        }
        if (t0 < 2048) out_Wd[t0] = Wdec[t0];
        return;
    }

    __shared__ float xs[16][128];
    __shared__ float we[16][132];
    __shared__ float wd[128][17];
    __shared__ float zs[16][16];

    {
        const float4* xv = (const float4*)x + (size_t)blk * 512;
        float* dst = &xs[0][0];
        float4 a = xv[tid], b = xv[tid + 256];
        dst[tid*4+0]=a.x; dst[tid*4+1]=a.y; dst[tid*4+2]=a.z; dst[tid*4+3]=a.w;
        dst[(tid+256)*4+0]=b.x; dst[(tid+256)*4+1]=b.y; dst[(tid+256)*4+2]=b.z; dst[(tid+256)*4+3]=b.w;
    }
    {
        const float4* wev = (const float4*)Wenc;
        #pragma unroll
        for (int h = 0; h < 2; ++h) {
            int vi = tid + h * 256;
            float4 v = wev[vi];
            int base = vi * 4, row = base >> 7, col = base & 127;
            we[row][col+0]=v.x; we[row][col+1]=v.y; we[row][col+2]=v.z; we[row][col+3]=v.w;
        }
    }
    {
        const float4* wdv = (const float4*)Wdec;
        #pragma unroll
        for (int h = 0; h < 2; ++h) {
            int vi = tid + h * 256;
            float4 v = wdv[vi];
            int base = vi * 4, row = base >> 4, col = base & 15;
            wd[row][col+0]=v.x; wd[row][col+1]=v.y; wd[row][col+2]=v.z; wd[row][col+3]=v.w;
        }
    }
    __syncthreads();

    {
        int r = tid >> 4, l = tid & 15;
        float s = 0.f;
        #pragma unroll 8
        for (int f = 0; f < 128; ++f) s += xs[r][f] * we[l][f];
        float zv = s + benc[l];
        zs[r][l] = zv;
        out_z[blk * 256 + tid] = zv;          // == (blk*16+r)*16 + l
    }
    __syncthreads();

    {   // transposed z copy for K2 (coalesced 64B runs)
        int l2 = tid >> 4, r2 = tid & 15;
        z_t[l2 * 32768 + blk * 16 + r2] = zs[r2][l2];
    }

    #pragma unroll
    for (int u = 0; u < 8; ++u) {
        int idx = u * 256 + tid;
        int rr = idx >> 7, f = idx & 127;
        float acc = bdec[f];
        #pragma unroll
        for (int ll = 0; ll < 16; ++ll) acc += zs[rr][ll] * wd[f][ll];
        out_xhat[(size_t)blk * 2048 + idx] = acc;
    }
}

// ======================================================================
// K2: Hilbert per (b,l), fp64 LDS FFT, bank-conflict-free layout
//     (round-15 proven form). Blocks >=256: jac range R2.
// ======================================================================
#define TWPAD(k) ((k) + ((k) >> 5))
#define CP(i)    ((i) + ((i) >> 4))

__global__ __launch_bounds__(1024) void k2_hilbert(
    const float* __restrict__ z_t, const double* __restrict__ twc_g,
    const double* __restrict__ tws_g, const float* __restrict__ Wenc,
    float* __restrict__ a_t, float* __restrict__ p_t,
    float* __restrict__ out_jac)
{
    __shared__ double2 c[2176];     // CP(2047)=2174 -> 2176; 34816 B
    __shared__ double twc_s[1056];  // TWPAD(1023)=1054 -> 1056; 8448 B
    __shared__ double tws_s[1056];  // 8448 B  (total 51712 B)

    int tid = threadIdx.x;
    if (blockIdx.x >= 256) {       // 512 writer blocks, nth = 524288
        jac_range(Wenc, out_jac, R2_LO, R2_HI, (blockIdx.x - 256) * 1024 + tid, 524288);
        return;
    }
    int b = blockIdx.x >> 4, l = blockIdx.x & 15;
    const size_t base = (size_t)l * 32768 + (size_t)b * 2048;
    const float* zp = z_t + base;

    {
        twc_s[TWPAD(tid)] = twc_g[tid];
        tws_s[TWPAD(tid)] = tws_g[tid];
    }
    {
        double2 v0; v0.x = (double)zp[tid];        v0.y = 0.0;
        double2 v1; v1.x = (double)zp[tid + 1024]; v1.y = 0.0;
        c[CP(tid)] = v0;
        c[CP(tid + 1024)] = v1;
    }
    __syncthreads();

    // forward DIF: u'=u+v, v'=(u-v)*W^(j*step)
    for (int half = 1024; half >= 1; half >>= 1) {
        int step = 1024 / half;
        int j = tid & (half - 1);
        int pos = ((tid - j) << 1) + j;
        int pa = CP(pos), pb = CP(pos + half);
        int ti = TWPAD(j * step);
        double2 u = c[pa], v = c[pb];
        double wc = twc_s[ti], wsn = tws_s[ti];
        double2 s, dsc;
        s.x = u.x + v.x;  s.y = u.y + v.y;
        double br = u.x - v.x, bi = u.y - v.y;
        dsc.x = br * wc - bi * wsn;
        dsc.y = br * wsn + bi * wc;
        c[pa] = s;
        c[pb] = dsc;
        __syncthreads();
    }

    // Hilbert filter in bitrev domain (k==0 <-> p==0, k>=1024 <-> p odd), 1/N folded
    #pragma unroll
    for (int h = 0; h < 2; ++h) {
        int t = tid + h * 1024;
        double sc = (t == 0 || (t & 1)) ? 0.0 : (2.0 / 2048.0);
        int ci = CP(t);
        double2 v = c[ci];
        v.x *= sc; v.y *= sc;
        c[ci] = v;
    }
    __syncthreads();

    // inverse DIT: t = v*conj(W); u'=u+t, v'=u-t
    for (int half = 1; half <= 1024; half <<= 1) {
        int step = 1024 / half;
        int j = tid & (half - 1);
        int pos = ((tid - j) << 1) + j;
        int pa = CP(pos), pb = CP(pos + half);
        int ti = TWPAD(j * step);
        double2 u = c[pa], v = c[pb];
        double wc = twc_s[ti], wsn = tws_s[ti];
        double tr = v.x * wc + v.y * wsn;     // v * conj(w)
        double ti2 = v.y * wc - v.x * wsn;
        double2 p0, p1;
        p0.x = u.x + tr; p0.y = u.y + ti2;
        p1.x = u.x - tr; p1.y = u.y - ti2;
        c[pa] = p0;
        c[pb] = p1;
        __syncthreads();
    }

    #pragma unroll
    for (int h = 0; h < 2; ++h) {
        int t = tid + h * 1024;
        double2 v = c[CP(t)];
        a_t[base + t] = (float)sqrt(v.x * v.x + v.y * v.y);
        p_t[base + t] = (float)atan2(v.y, v.x);
    }
}

// ======================================================================
// K3a: poly-feature partials. ROUND-16 CHANGE (only change vs r15):
//      4 points/thread — each weight row read once, applied to 4 accs.
//      256 compute blocks = 8 slices x 32 pt-groups (1024 pts/block).
//      LDS b128 count halves vs ppt=2 (1.98M -> 0.99M). Registers:
//      z[4][16]+acc[4][16]=128 + temps (~200) — no spill at 2 waves/SIMD.
//      Blocks >=256: jac range R3 (512 writer blocks, nth=131072).
// ======================================================================
#define EMIT4(EXPR) do {                                                    \
    if ((unsigned)(d - LO) < 121u) {                                        \
        float vv[4];                                                        \
        _Pragma("unroll") for (int p = 0; p < 4; ++p) vv[p] = (EXPR);       \
        int bb = (d - LO) << 4;                                             \
        _Pragma("unroll") for (int l = 0; l < 16; ++l) {                    \
            float w = lw[bb + l];                                           \
            _Pragma("unroll") for (int p = 0; p < 4; ++p)                   \
                acc[p][l] = fmaf(vv[p], w, acc[p][l]);                      \
        }                                                                   \
    }                                                                       \
    ++d;                                                                    \
} while (0)

__global__ __launch_bounds__(256) void k3_yhat(
    const float* __restrict__ z_ws, const float* __restrict__ wt,
    const float* __restrict__ Wenc,
    float* __restrict__ part, float* __restrict__ out_jac)
{
    __shared__ float lw[1936];                // 121 features x 16
    int tid = threadIdx.x;
    if (blockIdx.x >= 256) {                  // 512 writer blocks, nth = 131072
        jac_range(Wenc, out_jac, R3_LO, R3_HI, (blockIdx.x - 256) * 256 + tid, 131072);
        return;
    }
    int slice = blockIdx.x >> 5;              // 0..7
    int ptgrp = blockIdx.x & 31;              // 0..31
    int LO = slice * 121;
    int base = ptgrp * 1024;                  // 1024 points per block

    {   // stage slice weights: 484 float4
        const float4* src = (const float4*)(wt + LO * 16);
        float4* dst = (float4*)lw;
        for (int i = tid; i < 484; i += 256) dst[i] = src[i];
    }
    __syncthreads();

    float z[4][16], acc[4][16];
    #pragma unroll
    for (int p = 0; p < 4; ++p) {
        int bt = base + p * 256 + tid;
        const float4* zp = (const float4*)(z_ws + (size_t)bt * 16);
        #pragma unroll
        for (int q = 0; q < 4; ++q) {
            float4 v = zp[q];
            z[p][q*4+0]=v.x; z[p][q*4+1]=v.y; z[p][q*4+2]=v.z; z[p][q*4+3]=v.w;
        }
    }
    #pragma unroll
    for (int p = 0; p < 4; ++p)
        #pragma unroll
        for (int l = 0; l < 16; ++l) acc[p][l] = 0.f;

    int d = 0;
    #pragma unroll
    for (int i = 0; i < 16; ++i) EMIT4(z[p][i]);                          // deg 1 (folded)
    #pragma unroll
    for (int i = 0; i < 16; ++i)
        #pragma unroll
        for (int j = i; j < 16; ++j) EMIT4(z[p][i] * z[p][j]);            // deg 2
    #pragma unroll
    for (int i = 0; i < 16; ++i)
        #pragma unroll
        for (int j = i; j < 16; ++j)
            #pragma unroll
            for (int k = j; k < 16; ++k) EMIT4(z[p][i] * z[p][j] * z[p][k]); // deg 3

    #pragma unroll
    for (int p = 0; p < 4; ++p) {
        int bt = base + p * 256 + tid;
        float4* pp = (float4*)(part + (size_t)slice * 524288 + (size_t)bt * 16);
        #pragma unroll
        for (int q = 0; q < 4; ++q) {
            float4 v;
            v.x = acc[p][q*4+0]; v.y = acc[p][q*4+1];
            v.z = acc[p][q*4+2]; v.w = acc[p][q*4+3];
            pp[q] = v;
        }
    }
}

// ======================================================================
// K3b: tail — sum 8 partials + bias + amp/phase features (wt rows
//      984..1015) -> y_hat. 128 blocks, compute only. (round 11/15 form)
// ======================================================================
__global__ __launch_bounds__(256) void k3_tail(
    const float* __restrict__ part, const float* __restrict__ a_t,
    const float* __restrict__ p_t, const float* __restrict__ wt,
    const float* __restrict__ bsin, float* __restrict__ out_y)
{
    __shared__ float lw[512];                 // rows 984..1015 (amp 0..255, phase 256..511)
    int tid = threadIdx.x;
    if (tid < 128) {
        ((float4*)lw)[tid] = ((const float4*)(wt + 984 * 16))[tid];
    }
    __syncthreads();

    int bt = blockIdx.x * 256 + tid;
    float acc[16];
    {
        const float4* bp = (const float4*)bsin;
        #pragma unroll
        for (int q = 0; q < 4; ++q) {
            float4 v = bp[q];
            acc[q*4+0]=v.x; acc[q*4+1]=v.y; acc[q*4+2]=v.z; acc[q*4+3]=v.w;
        }
    }
    #pragma unroll
    for (int sl = 0; sl < 8; ++sl) {
        const float4* pp = (const float4*)(part + (size_t)sl * 524288 + (size_t)bt * 16);
        #pragma unroll
        for (int q = 0; q < 4; ++q) {
            float4 v = pp[q];
            acc[q*4+0]+=v.x; acc[q*4+1]+=v.y; acc[q*4+2]+=v.z; acc[q*4+3]+=v.w;
        }
    }
    #pragma unroll
    for (int i = 0; i < 16; ++i) {
        float av = a_t[(size_t)i * 32768 + bt];
        #pragma unroll
        for (int l = 0; l < 16; ++l) acc[l] = fmaf(av, lw[i * 16 + l], acc[l]);
    }
    #pragma unroll
    for (int i = 0; i < 16; ++i) {
        float pv = p_t[(size_t)i * 32768 + bt];
        #pragma unroll
        for (int l = 0; l < 16; ++l) acc[l] = fmaf(pv, lw[256 + i * 16 + l], acc[l]);
    }

    float4* yp = (float4*)(out_y + (size_t)bt * 16);
    #pragma unroll
    for (int q = 0; q < 4; ++q) {
        float4 v;
        v.x = acc[q*4+0]; v.y = acc[q*4+1]; v.z = acc[q*4+2]; v.w = acc[q*4+3];
        yp[q] = v;
    }
}

// ======================================================================
extern "C" void kernel_launch(void* const* d_in, const int* in_sizes, int n_in,
                              void* d_out, int out_size, void* d_ws, size_t ws_size,
                              hipStream_t stream)
{
    const float* x  = (const float*)d_in[0];
    const float* We = (const float*)d_in[1];
    const float* be = (const float*)d_in[2];
    const float* Wd = (const float*)d_in[3];
    const float* bd = (const float*)d_in[4];
    const float* Ws = (const float*)d_in[5];
    const float* bs = (const float*)d_in[6];

    float* out  = (float*)d_out;
    float* o_y  = out;                 // [16,2048,16]
    float* o_xh = out + 524288;        // [16,2048,128]
    float* o_z  = out + 4718592;       // [16,2048,16]
    float* o_j  = out + 5242880;       // [16,2048,16,128]  (268 MB)
    float* o_Ws = out + 72351744;      // [16,1016]
    float* o_Wd = out + 72368000;      // [128,16]

    float*  ws    = (float*)d_ws;
    float*  a_t   = ws + OFF_AT;
    float*  p_t   = ws + OFF_PT;
    float*  wt    = ws + OFF_WT;
    float*  z_t   = ws + OFF_ZT;
    double* twc_g = (double*)(ws + OFF_TWC);
    double* tws_g = (double*)(ws + OFF_TWS);
    float*  part  = ws + 1593216;      // [8][32768][16] = 4194304 f

    hipLaunchKernelGGL(k1_encdec, dim3(3140), dim3(256), 0, stream,
                       x, We, be, Wd, bd, Ws, o_z, o_xh, o_Ws, o_Wd,
                       z_t, wt, twc_g, tws_g, o_j);
    hipLaunchKernelGGL(k2_hilbert, dim3(768), dim3(1024), 0, stream,
                       z_t, twc_g, tws_g, We, a_t, p_t, o_j);
    hipLaunchKernelGGL(k3_yhat, dim3(768), dim3(256), 0, stream,
                       o_z, wt, We, part, o_j);
    hipLaunchKernelGGL(k3_tail, dim3(128), dim3(256), 0, stream,
                       part, a_t, p_t, wt, bs, o_y);
}

// Round 17
// 373.864 us; speedup vs baseline: 1.4025x; 1.4025x over previous
//
#include <hip/hip_runtime.h>
#include <math.h>

typedef unsigned short u16;
typedef unsigned int   u32;
typedef __attribute__((ext_vector_type(4))) float f32x4;   // native vec for nontemporal

// ---------------- scratch layout (fp32 offsets in d_ws; ws ~868 MB) ----------
#define OFF_AT    0          // |analytic|, [16][32768] (transposed)  524288 f
#define OFF_PT    524288     // angle,      [16][32768]               524288 f
#define OFF_WT    1048576    // W_sindy^T (deg1 folded), [1016][16]   16256 f
#define OFF_ZT    1064832    // z transposed [16][32768]              524288 f
#define OFF_TWC   1589120    // 1024 doubles (cos) = 2048 f
#define OFF_TWS   1591168    // 1024 doubles (sin)

// jac f4 ranges per kernel (exactly tile [0, 16777216)); all LO % 512 == 0
#define R1_LO 0
#define R1_HI 5592576
#define R2_LO 5592576
#define R2_HI 11185152
#define R3_LO 11185152
#define R3_HI 16777216

// jac[b,t,l,f] = W_enc[l,f]: flat f4 index i sources Wenc f4 (i & 511).
// Requires nth % 512 == 0 so the source index is loop-invariant.
__device__ __forceinline__ void jac_range(const float* __restrict__ Wenc,
                                          float* __restrict__ out_jac,
                                          int lo, int hi, int idx, int nth)
{
    const float* wsrc = Wenc + (size_t)((lo + idx) & 511) * 4;
    f32x4 w;
    w.x = wsrc[0]; w.y = wsrc[1]; w.z = wsrc[2]; w.w = wsrc[3];
    f32x4* j4 = (f32x4*)out_jac;
    for (int i = lo + idx; i < hi; i += nth)
        __builtin_nontemporal_store(w, j4 + i);
}

// ======================================================================
// K1: encoder + decoder; util blocks (2048..2115): passthroughs, folded
//     W_sindy^T, twiddles; writer blocks (>=2116): jac range R1.
// ======================================================================
__global__ __launch_bounds__(256) void k1_encdec(
    const float* __restrict__ x, const float* __restrict__ Wenc, const float* __restrict__ benc,
    const float* __restrict__ Wdec, const float* __restrict__ bdec,
    const float* __restrict__ Wsin,
    float* __restrict__ out_z, float* __restrict__ out_xhat,
    float* __restrict__ out_Ws, float* __restrict__ out_Wd,
    float* __restrict__ z_t, float* __restrict__ wt,
    double* __restrict__ twc_g, double* __restrict__ tws_g,
    float* __restrict__ out_jac)
{
    int tid = threadIdx.x;
    int blk = blockIdx.x;

    if (blk >= 2116) {       // 1024 writer blocks, nth = 262144 (512 | nth)
        jac_range(Wenc, out_jac, R1_LO, R1_HI, (blk - 2116) * 256 + tid, 262144);
        return;
    }
    if (blk >= 2048) {
        int t0 = (blk - 2048) * 256 + tid;   // 68 blocks -> 17408 threads
        if (t0 < 16256) {
            float v = Wsin[t0];
            out_Ws[t0] = v;                  // pass-through: ORIGINAL value
            int l = t0 / 1016;
            int d = t0 - l * 1016;
            // fold z-dup feature (968+d) into deg-1 row d
            if (d < 16) v += Wsin[t0 + 968];
            wt[d * 16 + l] = v;
        } else if (t0 < 17280) {             // 1024 twiddles, fp64, once
            int k = t0 - 16256;
            double ang = -6.283185307179586476925286766559 * (double)k / 2048.0;
            double s_, c_;
            sincos(ang, &s_, &c_);
            twc_g[k] = c_;
            tws_g[k] = s_;
        }
        if (t0 < 2048) out_Wd[t0] = Wdec[t0];
        return;
    }

    __shared__ float xs[16][128];
    __shared__ float we[16][132];
    __shared__ float wd[128][17];
    __shared__ float zs[16][16];

    {
        const float4* xv = (const float4*)x + (size_t)blk * 512;
        float* dst = &xs[0][0];
        float4 a = xv[tid], b = xv[tid + 256];
        dst[tid*4+0]=a.x; dst[tid*4+1]=a.y; dst[tid*4+2]=a.z; dst[tid*4+3]=a.w;
        dst[(tid+256)*4+0]=b.x; dst[(tid+256)*4+1]=b.y; dst[(tid+256)*4+2]=b.z; dst[(tid+256)*4+3]=b.w;
    }
    {
        const float4* wev = (const float4*)Wenc;
        #pragma unroll
        for (int h = 0; h < 2; ++h) {
            int vi = tid + h * 256;
            float4 v = wev[vi];
            int base = vi * 4, row = base >> 7, col = base & 127;
            we[row][col+0]=v.x; we[row][col+1]=v.y; we[row][col+2]=v.z; we[row][col+3]=v.w;
        }
    }
    {
        const float4* wdv = (const float4*)Wdec;
        #pragma unroll
        for (int h = 0; h < 2; ++h) {
            int vi = tid + h * 256;
            float4 v = wdv[vi];
            int base = vi * 4, row = base >> 4, col = base & 15;
            wd[row][col+0]=v.x; wd[row][col+1]=v.y; wd[row][col+2]=v.z; wd[row][col+3]=v.w;
        }
    }
    __syncthreads();

    {
        int r = tid >> 4, l = tid & 15;
        float s = 0.f;
        #pragma unroll 8
        for (int f = 0; f < 128; ++f) s += xs[r][f] * we[l][f];
        float zv = s + benc[l];
        zs[r][l] = zv;
        out_z[blk * 256 + tid] = zv;          // == (blk*16+r)*16 + l
    }
    __syncthreads();

    {   // transposed z copy for K2 (coalesced 64B runs)
        int l2 = tid >> 4, r2 = tid & 15;
        z_t[l2 * 32768 + blk * 16 + r2] = zs[r2][l2];
    }

    #pragma unroll
    for (int u = 0; u < 8; ++u) {
        int idx = u * 256 + tid;
        int rr = idx >> 7, f = idx & 127;
        float acc = bdec[f];
        #pragma unroll
        for (int ll = 0; ll < 16; ++ll) acc += zs[rr][ll] * wd[f][ll];
        out_xhat[(size_t)blk * 2048 + idx] = acc;
    }
}

// ======================================================================
// K2: Hilbert per (b,l), fp64 LDS FFT, bank-conflict-free layout
//     (round-15 proven form). Blocks >=256: jac range R2.
// ======================================================================
#define TWPAD(k) ((k) + ((k) >> 5))
#define CP(i)    ((i) + ((i) >> 4))

__global__ __launch_bounds__(1024) void k2_hilbert(
    const float* __restrict__ z_t, const double* __restrict__ twc_g,
    const double* __restrict__ tws_g, const float* __restrict__ Wenc,
    float* __restrict__ a_t, float* __restrict__ p_t,
    float* __restrict__ out_jac)
{
    __shared__ double2 c[2176];     // CP(2047)=2174 -> 2176; 34816 B
    __shared__ double twc_s[1056];  // TWPAD(1023)=1054 -> 1056; 8448 B
    __shared__ double tws_s[1056];  // 8448 B  (total 51712 B)

    int tid = threadIdx.x;
    if (blockIdx.x >= 256) {       // 512 writer blocks, nth = 524288
        jac_range(Wenc, out_jac, R2_LO, R2_HI, (blockIdx.x - 256) * 1024 + tid, 524288);
        return;
    }
    int b = blockIdx.x >> 4, l = blockIdx.x & 15;
    const size_t base = (size_t)l * 32768 + (size_t)b * 2048;
    const float* zp = z_t + base;

    {
        twc_s[TWPAD(tid)] = twc_g[tid];
        tws_s[TWPAD(tid)] = tws_g[tid];
    }
    {
        double2 v0; v0.x = (double)zp[tid];        v0.y = 0.0;
        double2 v1; v1.x = (double)zp[tid + 1024]; v1.y = 0.0;
        c[CP(tid)] = v0;
        c[CP(tid + 1024)] = v1;
    }
    __syncthreads();

    // forward DIF: u'=u+v, v'=(u-v)*W^(j*step)
    for (int half = 1024; half >= 1; half >>= 1) {
        int step = 1024 / half;
        int j = tid & (half - 1);
        int pos = ((tid - j) << 1) + j;
        int pa = CP(pos), pb = CP(pos + half);
        int ti = TWPAD(j * step);
        double2 u = c[pa], v = c[pb];
        double wc = twc_s[ti], wsn = tws_s[ti];
        double2 s, dsc;
        s.x = u.x + v.x;  s.y = u.y + v.y;
        double br = u.x - v.x, bi = u.y - v.y;
        dsc.x = br * wc - bi * wsn;
        dsc.y = br * wsn + bi * wc;
        c[pa] = s;
        c[pb] = dsc;
        __syncthreads();
    }

    // Hilbert filter in bitrev domain (k==0 <-> p==0, k>=1024 <-> p odd), 1/N folded
    #pragma unroll
    for (int h = 0; h < 2; ++h) {
        int t = tid + h * 1024;
        double sc = (t == 0 || (t & 1)) ? 0.0 : (2.0 / 2048.0);
        int ci = CP(t);
        double2 v = c[ci];
        v.x *= sc; v.y *= sc;
        c[ci] = v;
    }
    __syncthreads();

    // inverse DIT: t = v*conj(W); u'=u+t, v'=u-t
    for (int half = 1; half <= 1024; half <<= 1) {
        int step = 1024 / half;
        int j = tid & (half - 1);
        int pos = ((tid - j) << 1) + j;
        int pa = CP(pos), pb = CP(pos + half);
        int ti = TWPAD(j * step);
        double2 u = c[pa], v = c[pb];
        double wc = twc_s[ti], wsn = tws_s[ti];
        double tr = v.x * wc + v.y * wsn;     // v * conj(w)
        double ti2 = v.y * wc - v.x * wsn;
        double2 p0, p1;
        p0.x = u.x + tr; p0.y = u.y + ti2;
        p1.x = u.x - tr; p1.y = u.y - ti2;
        c[pa] = p0;
        c[pb] = p1;
        __syncthreads();
    }

    #pragma unroll
    for (int h = 0; h < 2; ++h) {
        int t = tid + h * 1024;
        double2 v = c[CP(t)];
        a_t[base + t] = (float)sqrt(v.x * v.x + v.y * v.y);
        p_t[base + t] = (float)atan2(v.y, v.x);
    }
}

// ======================================================================
// K3a: poly-feature partials (968 features, deg-1 pre-folded). 512 compute
//      blocks = 8 slices x 64 pt-groups, 2 pts/thread (2 blocks/CU,
//      launch_bounds(256,2) -> <=128 VGPR, no spill — ppt=4 hit the
//      256-VGPR cap and spilled 120 MB, r16). Blocks >=512: jac range R3.
// ======================================================================
#define EMIT2(EXPR) do {                                                    \
    if ((unsigned)(d - LO) < 121u) {                                        \
        float vv[2];                                                        \
        _Pragma("unroll") for (int p = 0; p < 2; ++p) vv[p] = (EXPR);       \
        int bb = (d - LO) << 4;                                             \
        _Pragma("unroll") for (int l = 0; l < 16; ++l) {                    \
            float w = lw[bb + l];                                           \
            acc[0][l] = fmaf(vv[0], w, acc[0][l]);                          \
            acc[1][l] = fmaf(vv[1], w, acc[1][l]);                          \
        }                                                                   \
    }                                                                       \
    ++d;                                                                    \
} while (0)

__global__ __launch_bounds__(256, 2) void k3_yhat(
    const float* __restrict__ z_ws, const float* __restrict__ wt,
    const float* __restrict__ Wenc,
    float* __restrict__ part, float* __restrict__ out_jac)
{
    __shared__ float lw[1936];                // 121 features x 16
    int tid = threadIdx.x;
    if (blockIdx.x >= 512) {                  // 1024 writer blocks, nth = 262144
        jac_range(Wenc, out_jac, R3_LO, R3_HI, (blockIdx.x - 512) * 256 + tid, 262144);
        return;
    }
    int slice = blockIdx.x >> 6;              // 0..7
    int ptgrp = blockIdx.x & 63;              // 0..63
    int LO = slice * 121;
    int base = ptgrp * 512;                   // 512 points per block

    {   // stage slice weights: 484 float4
        const float4* src = (const float4*)(wt + LO * 16);
        float4* dst = (float4*)lw;
        for (int i = tid; i < 484; i += 256) dst[i] = src[i];
    }
    __syncthreads();

    float z[2][16], acc[2][16];
    #pragma unroll
    for (int p = 0; p < 2; ++p) {
        int bt = base + p * 256 + tid;
        const float4* zp = (const float4*)(z_ws + (size_t)bt * 16);
        #pragma unroll
        for (int q = 0; q < 4; ++q) {
            float4 v = zp[q];
            z[p][q*4+0]=v.x; z[p][q*4+1]=v.y; z[p][q*4+2]=v.z; z[p][q*4+3]=v.w;
        }
    }
    #pragma unroll
    for (int p = 0; p < 2; ++p)
        #pragma unroll
        for (int l = 0; l < 16; ++l) acc[p][l] = 0.f;

    int d = 0;
    #pragma unroll
    for (int i = 0; i < 16; ++i) EMIT2(z[p][i]);                          // deg 1 (folded)
    #pragma unroll
    for (int i = 0; i < 16; ++i)
        #pragma unroll
        for (int j = i; j < 16; ++j) EMIT2(z[p][i] * z[p][j]);            // deg 2
    #pragma unroll
    for (int i = 0; i < 16; ++i)
        #pragma unroll
        for (int j = i; j < 16; ++j)
            #pragma unroll
            for (int k = j; k < 16; ++k) EMIT2(z[p][i] * z[p][j] * z[p][k]); // deg 3

    #pragma unroll
    for (int p = 0; p < 2; ++p) {
        int bt = base + p * 256 + tid;
        float4* pp = (float4*)(part + (size_t)slice * 524288 + (size_t)bt * 16);
        #pragma unroll
        for (int q = 0; q < 4; ++q) {
            float4 v;
            v.x = acc[p][q*4+0]; v.y = acc[p][q*4+1];
            v.z = acc[p][q*4+2]; v.w = acc[p][q*4+3];
            pp[q] = v;
        }
    }
}

// ======================================================================
// K3b: tail — sum 8 partials + bias + amp/phase features (wt rows
//      984..1015) -> y_hat. 128 blocks, compute only.
// ======================================================================
__global__ __launch_bounds__(256) void k3_tail(
    const float* __restrict__ part, const float* __restrict__ a_t,
    const float* __restrict__ p_t, const float* __restrict__ wt,
    const float* __restrict__ bsin, float* __restrict__ out_y)
{
    __shared__ float lw[512];                 // rows 984..1015 (amp 0..255, phase 256..511)
    int tid = threadIdx.x;
    if (tid < 128) {
        ((float4*)lw)[tid] = ((const float4*)(wt + 984 * 16))[tid];
    }
    __syncthreads();

    int bt = blockIdx.x * 256 + tid;
    float acc[16];
    {
        const float4* bp = (const float4*)bsin;
        #pragma unroll
        for (int q = 0; q < 4; ++q) {
            float4 v = bp[q];
            acc[q*4+0]=v.x; acc[q*4+1]=v.y; acc[q*4+2]=v.z; acc[q*4+3]=v.w;
        }
    }
    #pragma unroll
    for (int sl = 0; sl < 8; ++sl) {
        const float4* pp = (const float4*)(part + (size_t)sl * 524288 + (size_t)bt * 16);
        #pragma unroll
        for (int q = 0; q < 4; ++q) {
            float4 v = pp[q];
            acc[q*4+0]+=v.x; acc[q*4+1]+=v.y; acc[q*4+2]+=v.z; acc[q*4+3]+=v.w;
        }
    }
    #pragma unroll
    for (int i = 0; i < 16; ++i) {
        float av = a_t[(size_t)i * 32768 + bt];
        #pragma unroll
        for (int l = 0; l < 16; ++l) acc[l] = fmaf(av, lw[i * 16 + l], acc[l]);
    }
    #pragma unroll
    for (int i = 0; i < 16; ++i) {
        float pv = p_t[(size_t)i * 32768 + bt];
        #pragma unroll
        for (int l = 0; l < 16; ++l) acc[l] = fmaf(pv, lw[256 + i * 16 + l], acc[l]);
    }

    float4* yp = (float4*)(out_y + (size_t)bt * 16);
    #pragma unroll
    for (int q = 0; q < 4; ++q) {
        float4 v;
        v.x = acc[q*4+0]; v.y = acc[q*4+1]; v.z = acc[q*4+2]; v.w = acc[q*4+3];
        yp[q] = v;
    }
}

// ======================================================================
extern "C" void kernel_launch(void* const* d_in, const int* in_sizes, int n_in,
                              void* d_out, int out_size, void* d_ws, size_t ws_size,
                              hipStream_t stream)
{
    const float* x  = (const float*)d_in[0];
    const float* We = (const float*)d_in[1];
    const float* be = (const float*)d_in[2];
    const float* Wd = (const float*)d_in[3];
    const float* bd = (const float*)d_in[4];
    const float* Ws = (const float*)d_in[5];
    const float* bs = (const float*)d_in[6];

    float* out  = (float*)d_out;
    float* o_y  = out;                 // [16,2048,16]
    float* o_xh = out + 524288;        // [16,2048,128]
    float* o_z  = out + 4718592;       // [16,2048,16]
    float* o_j  = out + 5242880;       // [16,2048,16,128]  (268 MB)
    float* o_Ws = out + 72351744;      // [16,1016]
    float* o_Wd = out + 72368000;      // [128,16]

    float*  ws    = (float*)d_ws;
    float*  a_t   = ws + OFF_AT;
    float*  p_t   = ws + OFF_PT;
    float*  wt    = ws + OFF_WT;
    float*  z_t   = ws + OFF_ZT;
    double* twc_g = (double*)(ws + OFF_TWC);
    double* tws_g = (double*)(ws + OFF_TWS);
    float*  part  = ws + 1593216;      // [8][32768][16] = 4194304 f

    hipLaunchKernelGGL(k1_encdec, dim3(3140), dim3(256), 0, stream,
                       x, We, be, Wd, bd, Ws, o_z, o_xh, o_Ws, o_Wd,
                       z_t, wt, twc_g, tws_g, o_j);
    hipLaunchKernelGGL(k2_hilbert, dim3(768), dim3(1024), 0, stream,
                       z_t, twc_g, tws_g, We, a_t, p_t, o_j);
    hipLaunchKernelGGL(k3_yhat, dim3(1536), dim3(256), 0, stream,
                       o_z, wt, We, part, o_j);
    hipLaunchKernelGGL(k3_tail, dim3(128), dim3(256), 0, stream,
                       part, a_t, p_t, wt, bs, o_y);
}